// Round 2
// baseline (479.670 us; speedup 1.0000x reference)
//
#include <hip/hip_runtime.h>

#define CC   256
#define RC   32
#define SS   1024
#define B2   4
#define KV   768

// ---------------- Kernel 1: 2x2 pool + mix -> combined (4,256,32,32) ----------------
__global__ void k_pool_mix(const float* __restrict__ x, const float* __restrict__ mixp,
                           float* __restrict__ comb) {
    int idx = blockIdx.x * 256 + threadIdx.x;        // 0 .. 524287  (b,c,oh,ow)
    int ow = idx & 31;
    int t  = idx >> 5;
    int oh = t & 31;  t >>= 5;
    int c  = t & 255; int b = t >> 8;
    const float* px = x + (((size_t)(b * CC + c) * 64 + oh * 2) * 64 + ow * 2);
    float a = px[0], bb = px[1], cc = px[64], dd = px[65];
    float mx = fmaxf(fmaxf(a, bb), fmaxf(cc, dd));
    float av = 0.25f * (a + bb + cc + dd);
    float mw = 1.0f / (1.0f + expf(-mixp[0]));
    float x1 = mx + mw * (av - mx);
    float x2 = av + mw * (mx - av);
    int s = oh * 32 + ow;
    comb[((size_t)(b * 2 + 0) * CC + c) * SS + s] = x1;
    comb[((size_t)(b * 2 + 1) * CC + c) * SS + s] = x2;
}

// ---------------- Kernel 2: spatial mean -> pooled (4,256) ----------------
__global__ void k_pooled(const float* __restrict__ comb, float* __restrict__ pooled) {
    int bc = blockIdx.x;                              // b2*C + c
    const float* p = comb + (size_t)bc * SS;
    float sum = 0.f;
    for (int i = threadIdx.x; i < SS; i += 256) sum += p[i];
    __shared__ float red[256];
    red[threadIdx.x] = sum; __syncthreads();
    for (int off = 128; off > 0; off >>= 1) {
        if (threadIdx.x < off) red[threadIdx.x] += red[threadIdx.x + off];
        __syncthreads();
    }
    if (threadIdx.x == 0) pooled[bc] = red[0] * (1.0f / SS);
}

// ---------------- Kernel 3: gate MLP -> gate (4,) in {0,1} ----------------
__global__ void k_gate(const float* __restrict__ pooled, const float* __restrict__ w_s1,
                       const float* __restrict__ b_s1, const float* __restrict__ w_s2,
                       const float* __restrict__ b_s2, float* __restrict__ gate) {
    int b2 = blockIdx.x; int j = threadIdx.x;         // j in 0..127
    const float* pl = pooled + b2 * CC;
    float acc = b_s1[j];
    for (int c = 0; c < CC; c++) acc += pl[c] * w_s1[j * CC + c];
    float h1 = fmaxf(acc, 0.0f);
    __shared__ float red[128];
    red[j] = h1 * w_s2[j]; __syncthreads();
    for (int off = 64; off > 0; off >>= 1) {
        if (j < off) red[j] += red[j + off];
        __syncthreads();
    }
    if (j == 0) {
        float z = red[0] + b_s2[0];                   // sigmoid(z)>0.5 <=> z>0
        gate[b2] = (z > 0.0f) ? 1.0f : 0.0f;
    }
}

// ---------------- Kernel 4: out0 = max(g0*comb0, g1*comb1) -> d_out[0:524288] ----------------
__global__ void k_out0(const float* __restrict__ comb, const float* __restrict__ gate,
                       float* __restrict__ out) {
    int idx = blockIdx.x * 256 + threadIdx.x;         // (b,c,s)
    int s = idx & 1023;
    int t = idx >> 10;
    int c = t & 255; int b = t >> 8;
    float g0 = gate[b * 2 + 0], g1 = gate[b * 2 + 1];
    float v0 = g0 * comb[((size_t)(b * 2 + 0) * CC + c) * SS + s];
    float v1 = g1 * comb[((size_t)(b * 2 + 1) * CC + c) * SS + s];
    out[idx] = fmaxf(v0, v1);
}

// ---------------- Kernel 5: fused channel-reduce (256->32) + qkv ----------------
__global__ __launch_bounds__(256) void k_qkv(
        const float* __restrict__ comb, const float* __restrict__ w_red,
        const float* __restrict__ b_red, const float* __restrict__ w_qkv,
        const float* __restrict__ b_qkv,
        float* __restrict__ q, float* __restrict__ k, float* __restrict__ v) {
    __shared__ float wred[CC * RC];   // [c][r] transposed for broadcast, 32KB
    __shared__ float wq[96 * RC];     // 12KB
    int b2 = blockIdx.x >> 2; int tile = blockIdx.x & 3;
    int tid = threadIdx.x;
    for (int i = tid; i < CC * RC; i += 256) {
        int cc = i >> 5, rr = i & 31;
        wred[cc * RC + rr] = w_red[rr * CC + cc];
    }
    for (int i = tid; i < 96 * RC; i += 256) wq[i] = w_qkv[i];
    __syncthreads();
    int s = tile * 256 + tid;
    float xf[RC];
    #pragma unroll
    for (int r = 0; r < RC; r++) xf[r] = b_red[r];
    const float* pc = comb + (size_t)(b2 * CC) * SS + s;
    for (int c = 0; c < CC; c++) {
        float val = pc[(size_t)c * SS];               // coalesced across tid
        #pragma unroll
        for (int r = 0; r < RC; r++) xf[r] += val * wred[c * RC + r];
    }
    size_t base = (size_t)(b2 * SS + s) * RC;
    for (int j = 0; j < 96; j++) {
        float acc = b_qkv[j];
        #pragma unroll
        for (int r = 0; r < RC; r++) acc += xf[r] * wq[j * RC + r];
        if      (j < 32) q[base + j]      = acc;
        else if (j < 64) k[base + j - 32] = acc;
        else             v[base + j - 64] = acc;
    }
}

// ---------------- Kernel 6: per-row attention with exact top-768 (radix select) ----------------
__global__ __launch_bounds__(256) void k_attn(
        const float* __restrict__ q, const float* __restrict__ kk,
        const float* __restrict__ vv, float* __restrict__ mid) {
    __shared__ float sc[SS];                 // scores, later weights
    __shared__ unsigned int uk[SS];          // order-preserving keys
    __shared__ unsigned int hist[256];
    __shared__ float red[256];
    __shared__ __align__(16) float qs[RC];
    __shared__ float part[8][RC];
    __shared__ unsigned int sh_prefix;
    __shared__ int sh_k, sh_c1;
    __shared__ float sh_m, sh_denom;

    int b2 = blockIdx.x >> 10; int s = blockIdx.x & 1023;
    int tid = threadIdx.x;
    if (tid < RC) qs[tid] = q[(size_t)(b2 * SS + s) * RC + tid];
    __syncthreads();

    const float scale = 0.17677669529663687f;        // 1/sqrt(32)
    float lmax = -INFINITY;
    for (int t = tid; t < SS; t += 256) {
        const float4* kr4 = (const float4*)(kk + (size_t)(b2 * SS + t) * RC);
        float d = 0.f;
        #pragma unroll
        for (int r4 = 0; r4 < 8; r4++) {
            float4 kv4 = kr4[r4];
            float4 qv4 = ((const float4*)qs)[r4];
            d += qv4.x * kv4.x + qv4.y * kv4.y + qv4.z * kv4.z + qv4.w * kv4.w;
        }
        d *= scale;
        if (d != d) d = -INFINITY;                   // NaN -> -inf per reference
        sc[t] = d;
        unsigned int bb = __float_as_uint(d);
        uk[t] = bb ^ ((bb & 0x80000000u) ? 0xFFFFFFFFu : 0x80000000u);
        lmax = fmaxf(lmax, d);
    }
    // row max
    red[tid] = lmax; __syncthreads();
    for (int off = 128; off > 0; off >>= 1) {
        if (tid < off) red[tid] = fmaxf(red[tid], red[tid + off]);
        __syncthreads();
    }
    if (tid == 0) { sh_m = red[0]; sh_prefix = 0u; sh_k = KV; }
    __syncthreads();

    // 4-pass radix select for the KV-th largest key
    for (int pass = 3; pass >= 0; pass--) {
        int shift = pass * 8;
        hist[tid] = 0u;
        __syncthreads();
        unsigned int prefix = sh_prefix;
        for (int t = tid; t < SS; t += 256) {
            unsigned int u = uk[t];
            bool cand = (pass == 3) || ((u >> (shift + 8)) == (prefix >> (shift + 8)));
            if (cand) atomicAdd(&hist[(u >> shift) & 255u], 1u);
        }
        __syncthreads();
        if (tid == 0) {
            int kq = sh_k;
            for (int d = 255; d >= 0; d--) {
                int c = (int)hist[d];
                if (kq <= c) { sh_prefix = prefix | ((unsigned int)d << shift); sh_k = kq; break; }
                kq -= c;
            }
        }
        __syncthreads();
    }
    unsigned int utau = sh_prefix;
    float m = sh_m;

    // count strictly-greater (for tie handling by lowest index, matching top_k)
    int cg = 0;
    for (int t = tid; t < SS; t += 256) if (uk[t] > utau) cg++;
    red[tid] = (float)cg; __syncthreads();
    for (int off = 128; off > 0; off >>= 1) {
        if (tid < off) red[tid] += red[tid + off];
        __syncthreads();
    }
    if (tid == 0) sh_c1 = (int)red[0];
    __syncthreads();
    int extra = KV - sh_c1;

    // masked softmax weights (in-place over sc)
    float lden = 0.f;
    for (int t = tid; t < SS; t += 256) {
        unsigned int u = uk[t];
        float w = 0.f;
        if (u > utau) {
            w = expf(sc[t] - m);
        } else if (u == utau) {
            int rank = 0;
            for (int t2 = 0; t2 < t; t2++) if (uk[t2] == utau) rank++;
            if (rank < extra) w = expf(sc[t] - m);
        }
        lden += w;
        sc[t] = w;
    }
    red[tid] = lden; __syncthreads();
    for (int off = 128; off > 0; off >>= 1) {
        if (tid < off) red[tid] += red[tid + off];
        __syncthreads();
    }
    if (tid == 0) sh_denom = red[0];
    __syncthreads();

    // PV: out[r] = sum_t w[t] * v[t][r] / denom
    int r = tid & 31; int chunk = tid >> 5;
    float p = 0.f;
    for (int t = chunk * 128; t < chunk * 128 + 128; t++)
        p += sc[t] * vv[(size_t)(b2 * SS + t) * RC + r];
    part[chunk][r] = p; __syncthreads();
    if (tid < RC) {
        float o = 0.f;
        #pragma unroll
        for (int ch = 0; ch < 8; ch++) o += part[ch][tid];
        mid[(size_t)(b2 * SS + s) * RC + tid] = o / sh_denom;
    }
}

// ---------------- Kernel 7: projection 32->256 -> d_out[524288:] ----------------
__global__ __launch_bounds__(256) void k_proj(
        const float* __restrict__ mid, const float* __restrict__ w_red,
        float* __restrict__ attn_out) {
    __shared__ float wr[RC * CC];    // row-major [r][c], 32KB
    int b2 = blockIdx.x >> 2; int tile = blockIdx.x & 3;
    int tid = threadIdx.x;
    for (int i = tid; i < RC * CC; i += 256) wr[i] = w_red[i];
    __syncthreads();
    int s = tile * 256 + tid;
    float xr[RC];
    #pragma unroll
    for (int r = 0; r < RC; r++) xr[r] = mid[(size_t)(b2 * SS + s) * RC + r];
    for (int c = 0; c < CC; c++) {
        float acc = 0.f;
        #pragma unroll
        for (int r = 0; r < RC; r++) acc += xr[r] * wr[r * CC + c];
        attn_out[((size_t)(b2 * CC + c)) * SS + s] = acc;   // coalesced across tid
    }
}

extern "C" void kernel_launch(void* const* d_in, const int* in_sizes, int n_in,
                              void* d_out, int out_size, void* d_ws, size_t ws_size,
                              hipStream_t stream) {
    const float* x     = (const float*)d_in[0];
    const float* mixp  = (const float*)d_in[1];
    const float* w_red = (const float*)d_in[2];
    const float* b_red = (const float*)d_in[3];
    const float* w_qkv = (const float*)d_in[4];
    const float* b_qkv = (const float*)d_in[5];
    const float* w_s1  = (const float*)d_in[6];
    const float* b_s1  = (const float*)d_in[7];
    const float* w_s2  = (const float*)d_in[8];
    const float* b_s2  = (const float*)d_in[9];
    float* out = (float*)d_out;

    float* ws     = (float*)d_ws;
    float* comb   = ws;                 // 4*256*1024      = 1048576
    float* q      = comb + 1048576;     // 4*1024*32       = 131072
    float* k      = q + 131072;
    float* v      = k + 131072;
    float* mid    = v + 131072;         // 131072
    float* pooled = mid + 131072;       // 1024
    float* gate   = pooled + 1024;      // 4

    k_pool_mix<<<2048, 256, 0, stream>>>(x, mixp, comb);
    k_pooled  <<<1024, 256, 0, stream>>>(comb, pooled);
    k_gate    <<<4,    128, 0, stream>>>(pooled, w_s1, b_s1, w_s2, b_s2, gate);
    k_out0    <<<2048, 256, 0, stream>>>(comb, gate, out);
    k_qkv     <<<16,   256, 0, stream>>>(comb, w_red, b_red, w_qkv, b_qkv, q, k, v);
    k_attn    <<<4096, 256, 0, stream>>>(q, k, v, mid);
    k_proj    <<<16,   256, 0, stream>>>(mid, w_red, out + 524288);
}

// Round 3
// 318.805 us; speedup vs baseline: 1.5046x; 1.5046x over previous
//
#include <hip/hip_runtime.h>

#define CC   256
#define RC   32
#define SS   1024
#define B2   4
#define KV   768

// ---------------- Kernel 1: 2x2 pool + mix -> combined (4,256,32,32) ----------------
__global__ void k_pool_mix(const float* __restrict__ x, const float* __restrict__ mixp,
                           float* __restrict__ comb) {
    int idx = blockIdx.x * 256 + threadIdx.x;        // 0 .. 524287  (b,c,oh,ow)
    int ow = idx & 31;
    int t  = idx >> 5;
    int oh = t & 31;  t >>= 5;
    int c  = t & 255; int b = t >> 8;
    const float* px = x + (((size_t)(b * CC + c) * 64 + oh * 2) * 64 + ow * 2);
    float a = px[0], bb = px[1], cc = px[64], dd = px[65];
    float mx = fmaxf(fmaxf(a, bb), fmaxf(cc, dd));
    float av = 0.25f * (a + bb + cc + dd);
    float mw = 1.0f / (1.0f + expf(-mixp[0]));
    float x1 = mx + mw * (av - mx);
    float x2 = av + mw * (mx - av);
    int s = oh * 32 + ow;
    comb[((size_t)(b * 2 + 0) * CC + c) * SS + s] = x1;
    comb[((size_t)(b * 2 + 1) * CC + c) * SS + s] = x2;
}

// ---------------- Kernel 2: spatial mean -> pooled (4,256) ----------------
__global__ void k_pooled(const float* __restrict__ comb, float* __restrict__ pooled) {
    int bc = blockIdx.x;                              // b2*C + c
    const float* p = comb + (size_t)bc * SS;
    float sum = 0.f;
    for (int i = threadIdx.x; i < SS; i += 256) sum += p[i];
    __shared__ float red[256];
    red[threadIdx.x] = sum; __syncthreads();
    for (int off = 128; off > 0; off >>= 1) {
        if (threadIdx.x < off) red[threadIdx.x] += red[threadIdx.x + off];
        __syncthreads();
    }
    if (threadIdx.x == 0) pooled[bc] = red[0] * (1.0f / SS);
}

// ---------------- Kernel 3: gate MLP -> gate (4,) in {0,1} ----------------
__global__ void k_gate(const float* __restrict__ pooled, const float* __restrict__ w_s1,
                       const float* __restrict__ b_s1, const float* __restrict__ w_s2,
                       const float* __restrict__ b_s2, float* __restrict__ gate) {
    int b2 = blockIdx.x; int j = threadIdx.x;         // j in 0..127
    const float* pl = pooled + b2 * CC;
    float acc = b_s1[j];
    for (int c = 0; c < CC; c++) acc += pl[c] * w_s1[j * CC + c];
    float h1 = fmaxf(acc, 0.0f);
    __shared__ float red[128];
    red[j] = h1 * w_s2[j]; __syncthreads();
    for (int off = 64; off > 0; off >>= 1) {
        if (j < off) red[j] += red[j + off];
        __syncthreads();
    }
    if (j == 0) {
        float z = red[0] + b_s2[0];                   // sigmoid(z)>0.5 <=> z>0
        gate[b2] = (z > 0.0f) ? 1.0f : 0.0f;
    }
}

// ---------------- Kernel 4: out0 = max(g0*comb0, g1*comb1) -> d_out[0:524288] ----------------
__global__ void k_out0(const float* __restrict__ comb, const float* __restrict__ gate,
                       float* __restrict__ out) {
    int idx = blockIdx.x * 256 + threadIdx.x;         // (b,c,s)
    int s = idx & 1023;
    int t = idx >> 10;
    int c = t & 255; int b = t >> 8;
    float g0 = gate[b * 2 + 0], g1 = gate[b * 2 + 1];
    float v0 = g0 * comb[((size_t)(b * 2 + 0) * CC + c) * SS + s];
    float v1 = g1 * comb[((size_t)(b * 2 + 1) * CC + c) * SS + s];
    out[idx] = fmaxf(v0, v1);
}

// ---------------- Kernel 5: fused channel-reduce (256->32) + qkv (V stored transposed) ----------------
__global__ __launch_bounds__(256) void k_qkv(
        const float* __restrict__ comb, const float* __restrict__ w_red,
        const float* __restrict__ b_red, const float* __restrict__ w_qkv,
        const float* __restrict__ b_qkv,
        float* __restrict__ q, float* __restrict__ k, float* __restrict__ vt) {
    __shared__ float wred[CC * RC];   // [c][r] transposed for broadcast, 32KB
    __shared__ float wq[96 * RC];     // 12KB
    int b2 = blockIdx.x >> 2; int tile = blockIdx.x & 3;
    int tid = threadIdx.x;
    for (int i = tid; i < CC * RC; i += 256) {
        int cc = i >> 5, rr = i & 31;
        wred[cc * RC + rr] = w_red[rr * CC + cc];
    }
    for (int i = tid; i < 96 * RC; i += 256) wq[i] = w_qkv[i];
    __syncthreads();
    int s = tile * 256 + tid;
    float xf[RC];
    #pragma unroll
    for (int r = 0; r < RC; r++) xf[r] = b_red[r];
    const float* pc = comb + (size_t)(b2 * CC) * SS + s;
    for (int c = 0; c < CC; c++) {
        float val = pc[(size_t)c * SS];               // coalesced across tid
        #pragma unroll
        for (int r = 0; r < RC; r++) xf[r] += val * wred[c * RC + r];
    }
    size_t base = (size_t)(b2 * SS + s) * RC;
    for (int j = 0; j < 96; j++) {
        float acc = b_qkv[j];
        #pragma unroll
        for (int r = 0; r < RC; r++) acc += xf[r] * wq[j * RC + r];
        if      (j < 32) q[base + j]      = acc;
        else if (j < 64) k[base + j - 32] = acc;
        else             vt[((size_t)b2 * RC + (j - 64)) * SS + s] = acc;  // V^T: [b2][r][s]
    }
}

// ---------------- Kernel 6: per-WAVE attention row, exact top-768 (parallel radix select) ----------------
// Block = 256 threads = 4 waves; each wave owns one (b2,s) row. No serial sections.
__global__ __launch_bounds__(256) void k_attn(
        const float* __restrict__ q, const float* __restrict__ kk,
        const float* __restrict__ vt, float* __restrict__ mid) {
    __shared__ unsigned int uks[4][SS];       // per-wave: keys, later weights (16KB)
    __shared__ unsigned int hists[4][256];    // per-wave histogram (4KB)

    int wid  = threadIdx.x >> 6;
    int lane = threadIdx.x & 63;
    int row  = blockIdx.x * 4 + wid;          // 0..4095
    int b2 = row >> 10;
    unsigned int* uk   = uks[wid];
    unsigned int* hist = hists[wid];

    // Q row into registers (broadcast loads, all lanes same address)
    float qr[RC];
    {
        const float4* qp = (const float4*)(q + (size_t)row * RC);
        #pragma unroll
        for (int i = 0; i < 8; i++) {
            float4 t = qp[i];
            qr[4*i] = t.x; qr[4*i+1] = t.y; qr[4*i+2] = t.z; qr[4*i+3] = t.w;
        }
    }

    // ---- Phase A: scores -> order-preserving keys in LDS; running max ----
    const float scale = 0.17677669529663687f;   // 1/sqrt(32)
    float lmax = -INFINITY;
    #pragma unroll
    for (int i = 0; i < 16; i++) {
        int t = lane + 64 * i;
        const float4* kr = (const float4*)(kk + ((size_t)(b2 << 10) + t) * RC);
        float d = 0.f;
        #pragma unroll
        for (int j = 0; j < 8; j++) {
            float4 kv = kr[j];
            d += qr[4*j] * kv.x + qr[4*j+1] * kv.y + qr[4*j+2] * kv.z + qr[4*j+3] * kv.w;
        }
        d *= scale;
        if (d != d) d = -INFINITY;              // NaN -> -inf per reference
        unsigned int b = __float_as_uint(d);
        uk[t] = b ^ ((b & 0x80000000u) ? 0xFFFFFFFFu : 0x80000000u);
        lmax = fmaxf(lmax, d);
    }
    #pragma unroll
    for (int off = 32; off > 0; off >>= 1) lmax = fmaxf(lmax, __shfl_xor(lmax, off));

    // ---- Phase B: 4-pass radix select, wave-parallel scan ----
    unsigned int prefix = 0;
    int kq = KV;
    #pragma unroll
    for (int pass = 3; pass >= 0; pass--) {
        int shift = pass * 8;
        __syncthreads();                         // prior scan reads done before re-zero
        #pragma unroll
        for (int z = 0; z < 4; z++) hist[lane + 64 * z] = 0u;
        __syncthreads();
        unsigned int pfHi = prefix >> (shift + 8);
        #pragma unroll
        for (int i = 0; i < 16; i++) {
            unsigned int u = uk[lane + 64 * i];
            bool cand = (pass == 3) || ((u >> (shift + 8)) == pfHi);
            if (cand) atomicAdd(&hist[(u >> shift) & 255u], 1u);
        }
        __syncthreads();
        // lane owns bins 4*lane .. 4*lane+3 (descending digit = ascending bin)
        int h0 = (int)hist[4*lane], h1 = (int)hist[4*lane+1],
            h2 = (int)hist[4*lane+2], h3 = (int)hist[4*lane+3];
        int ls  = h0 + h1 + h2 + h3;
        int inc = ls;                            // inclusive suffix sum over lanes >= me
        #pragma unroll
        for (int off = 1; off < 64; off <<= 1) {
            int v = __shfl(inc, lane + off);
            inc += (lane + off < 64) ? v : 0;
        }
        int gex3 = inc - ls;                     // count of keys with digit > each bin
        int gex2 = gex3 + h3;
        int gex1 = gex2 + h2;
        int gex0 = gex1 + h1;
        int d = -1, g = 0;
        if      (kq > gex3 && kq <= gex3 + h3) { d = 4*lane + 3; g = gex3; }
        else if (kq > gex2 && kq <= gex2 + h2) { d = 4*lane + 2; g = gex2; }
        else if (kq > gex1 && kq <= gex1 + h1) { d = 4*lane + 1; g = gex1; }
        else if (kq > gex0 && kq <= gex0 + h0) { d = 4*lane + 0; g = gex0; }
        unsigned long long fm = __ballot(d >= 0);
        int src = (int)__builtin_ctzll(fm);
        d  = __shfl(d, src);
        g  = __shfl(g, src);
        kq -= g;
        prefix |= ((unsigned int)d) << shift;
    }
    unsigned int utau = prefix;
    int extra = kq;                              // # of ==utau to include (lowest index first)

    // ---- Phase C+D: tie ranks via ballots; masked softmax weights in-place ----
    float m = lmax, lden = 0.f;
    int eqBefore = 0;
    #pragma unroll
    for (int i = 0; i < 16; i++) {
        int t = lane + 64 * i;                   // stripe order == index order
        unsigned int u = uk[t];
        bool eq  = (u == utau);
        bool sel = (u > utau);
        unsigned long long bm = __ballot(eq);
        if (eq) {
            int rank = eqBefore + __popcll(bm & ((1ull << lane) - 1ull));
            sel = sel || (rank < extra);
        }
        eqBefore += (int)__popcll(bm);
        float wv = 0.f;
        if (sel) {
            unsigned int bb = u ^ ((u & 0x80000000u) ? 0x80000000u : 0xFFFFFFFFu);
            wv = expf(__uint_as_float(bb) - m);
        }
        lden += wv;
        uk[t] = __float_as_uint(wv);             // overwrite key with weight
    }
    #pragma unroll
    for (int off = 32; off > 0; off >>= 1) lden += __shfl_xor(lden, off);
    __syncthreads();                             // weights visible wave-wide

    // ---- Phase E: PV.  lane -> (r = lane&31, half = lane>>5); V^T float4 streams ----
    int r = lane & 31, half = lane >> 5;
    const float*  vrow = vt + ((size_t)b2 * RC + r) * SS + half * 512;
    const float*  wp   = (const float*)uk + half * 512;
    float a0 = 0.f, a1 = 0.f, a2 = 0.f, a3 = 0.f;
    #pragma unroll 8
    for (int t = 0; t < 512; t += 4) {
        float4 wv = *(const float4*)(wp + t);    // LDS broadcast within half
        float4 vv = *(const float4*)(vrow + t);  // global float4 stream
        a0 += wv.x * vv.x; a1 += wv.y * vv.y; a2 += wv.z * vv.z; a3 += wv.w * vv.w;
    }
    float p = (a0 + a1) + (a2 + a3);
    p += __shfl_down(p, 32);
    if (lane < RC) mid[(size_t)row * RC + lane] = p / lden;
}

// ---------------- Kernel 7: projection 32->256 -> d_out[524288:] ----------------
__global__ __launch_bounds__(256) void k_proj(
        const float* __restrict__ mid, const float* __restrict__ w_red,
        float* __restrict__ attn_out) {
    __shared__ float wr[RC * CC];    // row-major [r][c], 32KB
    int b2 = blockIdx.x >> 2; int tile = blockIdx.x & 3;
    int tid = threadIdx.x;
    for (int i = tid; i < RC * CC; i += 256) wr[i] = w_red[i];
    __syncthreads();
    int s = tile * 256 + tid;
    float xr[RC];
    #pragma unroll
    for (int r = 0; r < RC; r++) xr[r] = mid[(size_t)(b2 * SS + s) * RC + r];
    for (int c = 0; c < CC; c++) {
        float acc = 0.f;
        #pragma unroll
        for (int r = 0; r < RC; r++) acc += xr[r] * wr[r * CC + c];
        attn_out[((size_t)(b2 * CC + c)) * SS + s] = acc;   // coalesced across tid
    }
}

extern "C" void kernel_launch(void* const* d_in, const int* in_sizes, int n_in,
                              void* d_out, int out_size, void* d_ws, size_t ws_size,
                              hipStream_t stream) {
    const float* x     = (const float*)d_in[0];
    const float* mixp  = (const float*)d_in[1];
    const float* w_red = (const float*)d_in[2];
    const float* b_red = (const float*)d_in[3];
    const float* w_qkv = (const float*)d_in[4];
    const float* b_qkv = (const float*)d_in[5];
    const float* w_s1  = (const float*)d_in[6];
    const float* b_s1  = (const float*)d_in[7];
    const float* w_s2  = (const float*)d_in[8];
    const float* b_s2  = (const float*)d_in[9];
    float* out = (float*)d_out;

    float* ws     = (float*)d_ws;
    float* comb   = ws;                 // 4*256*1024      = 1048576
    float* q      = comb + 1048576;     // 4*1024*32       = 131072
    float* k      = q + 131072;
    float* vt     = k + 131072;         // V transposed [b2][r][s]
    float* mid    = vt + 131072;        // 131072
    float* pooled = mid + 131072;       // 1024
    float* gate   = pooled + 1024;      // 4

    k_pool_mix<<<2048, 256, 0, stream>>>(x, mixp, comb);
    k_pooled  <<<1024, 256, 0, stream>>>(comb, pooled);
    k_gate    <<<4,    128, 0, stream>>>(pooled, w_s1, b_s1, w_s2, b_s2, gate);
    k_out0    <<<2048, 256, 0, stream>>>(comb, gate, out);
    k_qkv     <<<16,   256, 0, stream>>>(comb, w_red, b_red, w_qkv, b_qkv, q, k, vt);
    k_attn    <<<1024, 256, 0, stream>>>(q, k, vt, mid);
    k_proj    <<<16,   256, 0, stream>>>(mid, w_red, out + 524288);
}

// Round 4
// 182.274 us; speedup vs baseline: 2.6316x; 1.7490x over previous
//
#include <hip/hip_runtime.h>

#define CC 256
#define RC 32
#define SS 1024
#define KV 768

// ---------- K1: 2x2 pool + mix -> comb (4,256,1024); fused pooled partial sums ----------
__global__ void k_pool_mix(const float* __restrict__ x, const float* __restrict__ mixp,
                           float* __restrict__ comb, float* __restrict__ pooled) {
    int tid = threadIdx.x;
    int idx = blockIdx.x * 256 + tid;             // bits: b(1)|c(8)|oh(5)|ow(5)
    int ow = idx & 31, t = idx >> 5;
    int oh = t & 31;  t >>= 5;
    int c = t & 255;  int b = t >> 8;
    const float* px = x + (((size_t)(b*CC + c)*64 + oh*2)*64 + ow*2);
    float2 r0 = *(const float2*)px;
    float2 r1 = *(const float2*)(px + 64);
    float mx = fmaxf(fmaxf(r0.x, r0.y), fmaxf(r1.x, r1.y));
    float av = 0.25f*(r0.x + r0.y + r1.x + r1.y);
    float mw = 1.f/(1.f + expf(-mixp[0]));
    float x1 = mx + mw*(av - mx);
    float x2 = av + mw*(mx - av);
    int s = oh*32 + ow;
    comb[((size_t)(b*2+0)*CC + c)*SS + s] = x1;
    comb[((size_t)(b*2+1)*CC + c)*SS + s] = x2;
    __shared__ float red[256];
    red[tid] = x1; __syncthreads();
    for (int off = 128; off; off >>= 1) { if (tid < off) red[tid] += red[tid+off]; __syncthreads(); }
    if (tid == 0) atomicAdd(&pooled[(b*2)*CC + c], red[0]);
    __syncthreads();
    red[tid] = x2; __syncthreads();
    for (int off = 128; off; off >>= 1) { if (tid < off) red[tid] += red[tid+off]; __syncthreads(); }
    if (tid == 0) atomicAdd(&pooled[(b*2+1)*CC + c], red[0]);
}

// ---------- K2: gate MLP (pooled holds SUMS; scale by 1/1024) ----------
__global__ void k_gate(const float* __restrict__ pooled, const float* __restrict__ w_s1,
                       const float* __restrict__ b_s1, const float* __restrict__ w_s2,
                       const float* __restrict__ b_s2, float* __restrict__ gate) {
    int b2 = blockIdx.x; int j = threadIdx.x;     // j in 0..127
    const float* pl = pooled + b2 * CC;
    float acc = 0.f;
    for (int c = 0; c < CC; c++) acc += pl[c] * w_s1[j*CC + c];
    float h1 = fmaxf(acc * (1.f/1024.f) + b_s1[j], 0.f);
    __shared__ float red[128];
    red[j] = h1 * w_s2[j]; __syncthreads();
    for (int off = 64; off; off >>= 1) { if (j < off) red[j] += red[j+off]; __syncthreads(); }
    if (j == 0) gate[b2] = (red[0] + b_s2[0] > 0.f) ? 1.f : 0.f;
}

// ---------- K3: out0 = max(g0*x1, g1*x2) ----------
__global__ void k_out0(const float* __restrict__ comb, const float* __restrict__ gate,
                       float* __restrict__ out) {
    int idx = blockIdx.x * 256 + threadIdx.x;     // (b,c,s)
    int s = idx & 1023;
    int t = idx >> 10;
    int c = t & 255; int b = t >> 8;
    float g0 = gate[b*2+0], g1 = gate[b*2+1];
    float v0 = g0 * comb[((size_t)(b*2+0)*CC + c)*SS + s];
    float v1 = g1 * comb[((size_t)(b*2+1)*CC + c)*SS + s];
    out[idx] = fmaxf(v0, v1);
}

// ---------- K4: channel-reduce (256->32) + qkv; 256 blocks of 16 s ----------
__global__ __launch_bounds__(256) void k_qkv(
        const float* __restrict__ comb, const float* __restrict__ w_red,
        const float* __restrict__ b_red, const float* __restrict__ w_qkv,
        const float* __restrict__ b_qkv,
        float* __restrict__ q, float* __restrict__ k, float* __restrict__ v) {
    __shared__ float wredT[CC*33];   // [c][r], stride 33 (conflict-free)
    __shared__ float wqP[96*33];
    int tid = threadIdx.x;
    int b2 = blockIdx.x >> 6; int tile = blockIdx.x & 63; int s0 = tile*16;
    for (int i = tid; i < CC*RC; i += 256) { int r = i >> 8, c = i & 255; wredT[c*33 + r] = w_red[i]; }
    for (int i = tid; i < 96*RC; i += 256) { int j = i >> 5, r = i & 31; wqP[j*33 + r] = w_qkv[i]; }
    __syncthreads();
    int s_loc = tid >> 4, p = tid & 15;
    int s = s0 + s_loc;
    float xf[RC];
    #pragma unroll
    for (int r = 0; r < RC; r++) xf[r] = 0.f;
    const float* pc = comb + (size_t)(b2*CC)*SS + s;
    #pragma unroll
    for (int ci = 0; ci < 16; ci++) {
        int c = p + 16*ci;
        float val = pc[(size_t)c * SS];
        #pragma unroll
        for (int r = 0; r < RC; r++) xf[r] += val * wredT[c*33 + r];
    }
    #pragma unroll
    for (int m1 = 1; m1 <= 8; m1 <<= 1) {
        #pragma unroll
        for (int r = 0; r < RC; r++) xf[r] += __shfl_xor(xf[r], m1);
    }
    #pragma unroll
    for (int r = 0; r < RC; r++) xf[r] += b_red[r];
    size_t base = (size_t)(b2*SS + s)*RC;
    #pragma unroll
    for (int jj = 0; jj < 6; jj++) {
        int j = p*6 + jj;
        float acc = b_qkv[j];
        #pragma unroll
        for (int r = 0; r < RC; r++) acc += xf[r]*wqP[j*33 + r];
        if      (j < 32) q[base + j]      = acc;
        else if (j < 64) k[base + j - 32] = acc;
        else             v[base + j - 64] = acc;
    }
}

// ---------- K5: attention, 256 blocks; 16 rows/block, 16 lanes/row; LDS-staged K/V ----------
__global__ __launch_bounds__(256, 1) void k_attn(
        const float* __restrict__ qg, const float* __restrict__ kg,
        const float* __restrict__ vg, float* __restrict__ mid) {
    __shared__ float Ks[128*36];                  // one 128-row chunk, stride 36 floats
    int tid = threadIdx.x;
    int b2 = blockIdx.x >> 6; int tile = blockIdx.x & 63;
    int r = tid >> 4, c = tid & 15;
    int grow = b2*SS + tile*16 + r;               // global row

    float qreg[RC];
    { const float4* qp = (const float4*)(qg + (size_t)grow*RC);
      #pragma unroll
      for (int i = 0; i < 8; i++) { float4 t4 = qp[i]; qreg[4*i]=t4.x; qreg[4*i+1]=t4.y; qreg[4*i+2]=t4.z; qreg[4*i+3]=t4.w; } }

    const float4* ksrc = (const float4*)(kg + (size_t)(b2*SS)*RC);
    const float4* vsrc = (const float4*)(vg + (size_t)(b2*SS)*RC);
    float4 stg[4];
    #pragma unroll
    for (int kk = 0; kk < 4; kk++) stg[kk] = ksrc[tid + 256*kk];

    unsigned int u[64];
    float lmax = -INFINITY;
    const float scale = 0.17677669529663687f;     // 1/sqrt(32)

    #pragma unroll
    for (int ch = 0; ch < 8; ch++) {
        __syncthreads();
        #pragma unroll
        for (int kk = 0; kk < 4; kk++) {
            int idx4 = tid + 256*kk;
            *(float4*)&Ks[(idx4 >> 3)*36 + (idx4 & 7)*4] = stg[kk];
        }
        __syncthreads();
        if (ch < 7) {
            #pragma unroll
            for (int kk = 0; kk < 4; kk++) stg[kk] = ksrc[(ch+1)*1024 + tid + 256*kk];
        } else {
            #pragma unroll
            for (int kk = 0; kk < 4; kk++) stg[kk] = vsrc[tid + 256*kk];   // prefetch V chunk 0
        }
        #pragma unroll
        for (int qq = 0; qq < 8; qq++) {
            int cl = c + 16*qq;
            const float4* kr = (const float4*)&Ks[cl*36];
            float a0=0.f, a1=0.f, a2=0.f, a3=0.f;
            #pragma unroll
            for (int k4 = 0; k4 < 8; k4++) {
                float4 kv4 = kr[k4];
                a0 += qreg[4*k4]*kv4.x;   a1 += qreg[4*k4+1]*kv4.y;
                a2 += qreg[4*k4+2]*kv4.z; a3 += qreg[4*k4+3]*kv4.w;
            }
            float d = ((a0+a1)+(a2+a3))*scale;
            if (d != d) d = -INFINITY;            // NaN -> -inf
            lmax = fmaxf(lmax, d);
            unsigned int bb = __float_as_uint(d);
            u[ch*8+qq] = bb ^ ((bb & 0x80000000u) ? 0xFFFFFFFFu : 0x80000000u);
        }
    }

    #pragma unroll
    for (int m1 = 1; m1 <= 8; m1 <<= 1) lmax = fmaxf(lmax, __shfl_xor(lmax, m1));
    float m = lmax;

    // ---- exact top-768 threshold: bitwise binary search on uint keys, early exit ----
    unsigned int p = 0u, utau = 0u; bool found = false;
    for (int bit = 31; bit >= 0; --bit) {
        if (found) break;
        unsigned int cand = p | (1u << bit);
        int cnt = 0;
        #pragma unroll
        for (int i = 0; i < 64; i++) cnt += (u[i] >= cand) ? 1 : 0;
        #pragma unroll
        for (int m1 = 1; m1 <= 8; m1 <<= 1) cnt += __shfl_xor(cnt, m1);
        if (cnt >= KV) {
            if (cnt == KV) {                      // tau = min key >= cand
                unsigned int um = 0xFFFFFFFFu;
                #pragma unroll
                for (int i = 0; i < 64; i++) if (u[i] >= cand && u[i] < um) um = u[i];
                #pragma unroll
                for (int m1 = 1; m1 <= 8; m1 <<= 1) {
                    unsigned int o = (unsigned int)__shfl_xor((int)um, m1);
                    um = (o < um) ? o : um;
                }
                utau = um; found = true;
            } else p = cand;
        }
    }
    if (!found) utau = p;

    int cg = 0, eqc = 0;
    #pragma unroll
    for (int i = 0; i < 64; i++) { cg += (u[i] > utau) ? 1 : 0; eqc += (u[i] == utau) ? 1 : 0; }
    #pragma unroll
    for (int m1 = 1; m1 <= 8; m1 <<= 1) { cg += __shfl_xor(cg, m1); eqc += __shfl_xor(eqc, m1); }
    int extra = KV - cg;

    float w[64]; float den = 0.f;
    if (extra == eqc) {                           // common: include all ties
        #pragma unroll
        for (int i = 0; i < 64; i++) {
            bool sel = (u[i] >= utau);
            unsigned int bb = u[i] ^ ((u[i] & 0x80000000u) ? 0x80000000u : 0xFFFFFFFFu);
            float wv = sel ? expf(__uint_as_float(bb) - m) : 0.f;
            w[i] = wv; den += wv;
        }
    } else {                                      // rare: partial ties, rank by lowest index
        int prior = 0;
        #pragma unroll
        for (int i = 0; i < 64; i++) {            // slot i = col (c + 16*(i&7) + 128*(i>>3)); i-major order ok
            bool eq = (u[i] == utau);
            unsigned long long bm = __ballot(eq);
            unsigned int bm16 = (unsigned int)((bm >> (tid & 48)) & 0xFFFFull);
            int rank = prior + __popc(bm16 & ((1u << c) - 1u));
            prior += __popc(bm16);
            bool sel = (u[i] > utau) || (eq && rank < extra);
            unsigned int bb = u[i] ^ ((u[i] & 0x80000000u) ? 0x80000000u : 0xFFFFFFFFu);
            float wv = sel ? expf(__uint_as_float(bb) - m) : 0.f;
            w[i] = wv; den += wv;
        }
    }
    #pragma unroll
    for (int m1 = 1; m1 <= 8; m1 <<= 1) den += __shfl_xor(den, m1);

    // ---- PV over V chunks (V chunk 0 already in stg) ----
    float acc[RC];
    #pragma unroll
    for (int i = 0; i < RC; i++) acc[i] = 0.f;
    #pragma unroll
    for (int ch = 0; ch < 8; ch++) {
        __syncthreads();
        #pragma unroll
        for (int kk = 0; kk < 4; kk++) {
            int idx4 = tid + 256*kk;
            *(float4*)&Ks[(idx4 >> 3)*36 + (idx4 & 7)*4] = stg[kk];
        }
        __syncthreads();
        if (ch < 7) {
            #pragma unroll
            for (int kk = 0; kk < 4; kk++) stg[kk] = vsrc[(ch+1)*1024 + tid + 256*kk];
        }
        #pragma unroll
        for (int qq = 0; qq < 8; qq++) {
            int cl = c + 16*qq;
            float wj = w[ch*8 + qq];
            const float4* vr = (const float4*)&Ks[cl*36];
            #pragma unroll
            for (int k4 = 0; k4 < 8; k4++) {
                float4 vv = vr[k4];
                acc[4*k4]   += wj*vv.x; acc[4*k4+1] += wj*vv.y;
                acc[4*k4+2] += wj*vv.z; acc[4*k4+3] += wj*vv.w;
            }
        }
    }
    #pragma unroll
    for (int m1 = 1; m1 <= 8; m1 <<= 1) {
        #pragma unroll
        for (int i = 0; i < RC; i++) acc[i] += __shfl_xor(acc[i], m1);
    }
    if (c == 0) {
        float rden = 1.f/den;
        float4* dst = (float4*)(mid + (size_t)grow*RC);
        #pragma unroll
        for (int k4 = 0; k4 < 8; k4++)
            dst[k4] = make_float4(acc[4*k4]*rden, acc[4*k4+1]*rden, acc[4*k4+2]*rden, acc[4*k4+3]*rden);
    }
}

// ---------- K6: projection 32->256; 128 blocks ----------
__global__ __launch_bounds__(256) void k_proj(
        const float* __restrict__ mid, const float* __restrict__ w_red,
        float* __restrict__ attn_out) {
    __shared__ float wr[32*32];
    int tid = threadIdx.x;
    int b2 = blockIdx.x >> 5; int st = (blockIdx.x >> 3) & 3; int cch = blockIdx.x & 7;
    for (int i = tid; i < 1024; i += 256) {
        int rr = i >> 5, cc = i & 31;
        wr[i] = w_red[rr*CC + cch*32 + cc];
    }
    __syncthreads();
    int s = st*256 + tid;
    float xr[RC];
    const float4* mp = (const float4*)(mid + (size_t)(b2*SS + s)*RC);
    #pragma unroll
    for (int i = 0; i < 8; i++) { float4 t4 = mp[i]; xr[4*i]=t4.x; xr[4*i+1]=t4.y; xr[4*i+2]=t4.z; xr[4*i+3]=t4.w; }
    #pragma unroll
    for (int cc = 0; cc < 32; cc++) {
        float a = 0.f;
        #pragma unroll
        for (int rr = 0; rr < RC; rr++) a += xr[rr]*wr[rr*32 + cc];
        attn_out[((size_t)(b2*CC) + cch*32 + cc)*SS + s] = a;   // coalesced across tid
    }
}

extern "C" void kernel_launch(void* const* d_in, const int* in_sizes, int n_in,
                              void* d_out, int out_size, void* d_ws, size_t ws_size,
                              hipStream_t stream) {
    const float* x     = (const float*)d_in[0];
    const float* mixp  = (const float*)d_in[1];
    const float* w_red = (const float*)d_in[2];
    const float* b_red = (const float*)d_in[3];
    const float* w_qkv = (const float*)d_in[4];
    const float* b_qkv = (const float*)d_in[5];
    const float* w_s1  = (const float*)d_in[6];
    const float* b_s1  = (const float*)d_in[7];
    const float* w_s2  = (const float*)d_in[8];
    const float* b_s2  = (const float*)d_in[9];
    float* out = (float*)d_out;

    float* ws     = (float*)d_ws;
    float* comb   = ws;                 // 1048576
    float* q      = comb + 1048576;     // 131072
    float* k      = q + 131072;         // 131072
    float* v      = k + 131072;         // 131072
    float* mid    = v + 131072;         // 131072
    float* pooled = mid + 131072;       // 1024
    float* gate   = pooled + 1024;      // 4

    hipMemsetAsync(pooled, 0, 1024*sizeof(float), stream);
    k_pool_mix<<<2048, 256, 0, stream>>>(x, mixp, comb, pooled);
    k_gate    <<<4,    128, 0, stream>>>(pooled, w_s1, b_s1, w_s2, b_s2, gate);
    k_out0    <<<2048, 256, 0, stream>>>(comb, gate, out);
    k_qkv     <<<256,  256, 0, stream>>>(comb, w_red, b_red, w_qkv, b_qkv, q, k, v);
    k_attn    <<<256,  256, 0, stream>>>(q, k, v, mid);
    k_proj    <<<128,  256, 0, stream>>>(mid, w_red, out + 524288);
}